// Round 1
// baseline (241.213 us; speedup 1.0000x reference)
//
#include <hip/hip_runtime.h>
#include <math.h>

#define SIN_ 128
#define TEMB_ 512
#define EMB_ 1024
#define S_ 64
#define B_ 4
#define T_ 4096
#define NROW (B_*T_)          // 16384
#define L_ 64                 // scan chunk length
#define NC_ (T_/L_)           // 64 chunks per batch row

// workspace layout (float offsets)
#define WS_T1     0
#define WS_T2     512
#define WS_DELTA  1024
#define WS_DA     1088
#define WS_ABAR   1152
#define WS_EL     1216
#define WS_FAC    1280                    // L_*S_ = 4096
#define WS_D      5376                    // 1024
#define WS_BM     6400                    // S_*EMB_ = 65536 (gated, delta NOT applied)
#define WS_C      71936                   // EMB_*S_ = 65536
#define WS_HLOC   137472                  // NROW*S_ = 1048576
#define WS_CHEND  1186048                 // B_*NC_*S_ = 16384
#define WS_CARRY  1202432                 // 16384
#define WS_TOTAL  1218816                 // ~4.9 MB

__device__ __forceinline__ float sigmoidf_(float x){ return 1.f/(1.f+expf(-x)); }
__device__ __forceinline__ float softplusf_(float x){ return x>20.f ? x : log1pf(expf(x)); }

// ---- Ka: t1 = silu(te @ W1 + b1) ----
__global__ void k_t1(const float* __restrict__ te, const float* __restrict__ W1,
                     const float* __restrict__ b1, float* __restrict__ ws){
  __shared__ float ste[SIN_];
  int tid = threadIdx.x;                 // 128 threads, 4 blocks
  ste[tid] = te[tid];
  __syncthreads();
  int j = blockIdx.x*128 + tid;
  float a = b1[j];
  #pragma unroll 8
  for (int i=0;i<SIN_;i++) a += ste[i]*W1[i*TEMB_ + j];
  ws[WS_T1 + j] = a * sigmoidf_(a);
}

// ---- Kb: t2 = t1 @ W2 + b2 ----
__global__ void k_t2(const float* __restrict__ W2, const float* __restrict__ b2,
                     float* __restrict__ ws){
  __shared__ float st1[TEMB_];
  int tid = threadIdx.x;                 // 128 threads, 4 blocks
  for (int i=tid;i<TEMB_;i+=128) st1[i] = ws[WS_T1 + i];
  __syncthreads();
  int j = blockIdx.x*128 + tid;
  float a = b2[j];
  #pragma unroll 8
  for (int i=0;i<TEMB_;i++) a += st1[i]*W2[i*TEMB_ + j];
  ws[WS_T2 + j] = a;
}

// ---- Kc: all t2/te-dependent parameters ----
// blocks 0..255   : Bm[s][e]  (gated B, delta applied later)
// blocks 256..511 : C[e][s]
// blocks 512..515 : D[e]
// block  516      : A, delta, dA, abar, eL, fac table
__global__ __launch_bounds__(256) void k_params(
    const float* __restrict__ te,
    const float* __restrict__ WA, const float* __restrict__ bA,
    const float* __restrict__ WB, const float* __restrict__ bB,
    const float* __restrict__ WC, const float* __restrict__ bC,
    const float* __restrict__ WD, const float* __restrict__ bD,
    const float* __restrict__ Wdl, const float* __restrict__ bdl,
    const float* __restrict__ MA, const float* __restrict__ mA,
    const float* __restrict__ MB, const float* __restrict__ mB,
    const float* __restrict__ MC, const float* __restrict__ mC,
    const float* __restrict__ MD, const float* __restrict__ mD,
    const float* __restrict__ Mdl, const float* __restrict__ mdl,
    float* __restrict__ ws){
  __shared__ float st2[TEMB_];
  __shared__ float ste[SIN_];
  int tid = threadIdx.x;
  st2[tid] = ws[WS_T2 + tid];
  st2[tid+256] = ws[WS_T2 + tid + 256];
  if (tid < SIN_) ste[tid] = te[tid];
  __syncthreads();
  int bb = blockIdx.x;
  if (bb < 256){
    int flat = bb*256 + tid;             // s*1024 + e
    float a = bB[flat];
    #pragma unroll 8
    for (int i=0;i<TEMB_;i++) a += st2[i]*WB[i*65536 + flat];
    float g = mB[flat];
    #pragma unroll 8
    for (int i=0;i<SIN_;i++) g += ste[i]*MB[i*65536 + flat];
    ws[WS_BM + flat] = a * sigmoidf_(g);
  } else if (bb < 512){
    int flat = (bb-256)*256 + tid;       // e*64 + s
    float a = bC[flat];
    #pragma unroll 8
    for (int i=0;i<TEMB_;i++) a += st2[i]*WC[i*65536 + flat];
    float g = mC[flat];
    #pragma unroll 8
    for (int i=0;i<SIN_;i++) g += ste[i]*MC[i*65536 + flat];
    ws[WS_C + flat] = a * sigmoidf_(g);
  } else if (bb < 516){
    int e = (bb-512)*256 + tid;
    float a = bD[e];
    #pragma unroll 8
    for (int i=0;i<TEMB_;i++) a += st2[i]*WD[i*EMB_ + e];
    float g = mD[e];
    #pragma unroll 8
    for (int i=0;i<SIN_;i++) g += ste[i]*MD[i*EMB_ + e];
    ws[WS_D + e] = a * sigmoidf_(g);
  } else {
    __shared__ float sA[S_], sd[S_], sda[S_];
    if (tid < 64){
      int s = tid;
      float a = bA[s];
      for (int i=0;i<TEMB_;i++) a += st2[i]*WA[i*S_ + s];
      float g = mA[s];
      for (int i=0;i<SIN_;i++) g += ste[i]*MA[i*S_ + s];
      sA[s] = -softplusf_(a) * sigmoidf_(g);
    } else if (tid < 128){
      int s = tid - 64;
      float a = bdl[s];
      for (int i=0;i<TEMB_;i++) a += st2[i]*Wdl[i*S_ + s];
      float g = mdl[s];
      for (int i=0;i<SIN_;i++) g += ste[i]*Mdl[i*S_ + s];
      sd[s] = (softplusf_(a) + 1e-4f) * sigmoidf_(g);
    }
    __syncthreads();
    if (tid < 64){
      int s = tid;
      float da = sd[s]*sA[s];
      sda[s] = da;
      ws[WS_DELTA+s] = sd[s];
      ws[WS_DA+s]    = da;
      ws[WS_ABAR+s]  = expf(da);
      ws[WS_EL+s]    = expf((float)L_*da);
    }
    __syncthreads();
    for (int idx=tid; idx<L_*S_; idx+=256){
      int tl = idx>>6, s = idx&63;
      ws[WS_FAC+idx] = expf((float)(tl+1)*sda[s]);
    }
  }
}

// ---- Kd: per-(b,chunk) u = x @ Bm^T (scaled by delta), then zero-state local scan ----
__global__ __launch_bounds__(256) void k_scan(const float* __restrict__ x, float* __restrict__ ws){
  __shared__ float Xs[64][65];
  __shared__ float Bs[64][65];
  __shared__ float Us[64][65];
  __shared__ float sdl[S_], sab[S_];
  int tid = threadIdx.x;
  int bb = blockIdx.x;                       // b*64 + c
  int row0 = (bb>>6)*T_ + (bb&63)*64;
  if (tid<64){ sdl[tid]=ws[WS_DELTA+tid]; sab[tid]=ws[WS_ABAR+tid]; }
  float acc[4][4];
  #pragma unroll
  for (int i=0;i<4;i++)
    #pragma unroll
    for (int j=0;j<4;j++) acc[i][j]=0.f;
  int ty = tid>>4, tx = tid&15;
  for (int kk=0; kk<EMB_; kk+=64){
    #pragma unroll
    for (int t=0;t<16;t++){
      int fl = t*256+tid; int rr = fl>>6, k = fl&63;
      Xs[rr][k] = x[(row0+rr)*EMB_ + kk + k];
      Bs[rr][k] = ws[WS_BM + rr*EMB_ + kk + k];   // rr = s
    }
    __syncthreads();
    #pragma unroll 4
    for (int k=0;k<64;k++){
      float xv[4], bv[4];
      #pragma unroll
      for (int i=0;i<4;i++) xv[i]=Xs[4*ty+i][k];
      #pragma unroll
      for (int j=0;j<4;j++) bv[j]=Bs[4*tx+j][k];
      #pragma unroll
      for (int i=0;i<4;i++)
        #pragma unroll
        for (int j=0;j<4;j++) acc[i][j] += xv[i]*bv[j];
    }
    __syncthreads();
  }
  #pragma unroll
  for (int i=0;i<4;i++)
    #pragma unroll
    for (int j=0;j<4;j++)
      Us[4*ty+i][4*tx+j] = acc[i][j]*sdl[4*tx+j];
  __syncthreads();
  if (tid<64){
    int s = tid; float h = 0.f, ab = sab[s];
    for (int t=0;t<64;t++){
      h = ab*h + Us[t][s];
      ws[WS_HLOC + (row0+t)*S_ + s] = h;
    }
    ws[WS_CHEND + bb*S_ + s] = h;
  }
}

// ---- Ke: chain chunk boundary states ----
__global__ void k_carry(float* __restrict__ ws){
  __shared__ float ch[B_*NC_*S_];            // 64 KB
  int tid = threadIdx.x;                     // 256 = (b,s)
  for (int i=tid;i<B_*NC_*S_;i+=256) ch[i] = ws[WS_CHEND + i];
  __syncthreads();
  int b = tid>>6, s = tid&63;
  float el = ws[WS_EL + s];
  float carry = 0.f;
  #pragma unroll 8
  for (int c=0;c<NC_;c++){
    int idx = (b*NC_ + c)*S_ + s;
    ws[WS_CARRY + idx] = carry;
    carry = el*carry + ch[idx];
  }
}

// ---- Kf: out = (hloc + fac*carry) @ C^T + D*x ----
__global__ __launch_bounds__(256) void k_out(const float* __restrict__ x,
                                             const float* __restrict__ ws,
                                             float* __restrict__ out){
  __shared__ float Ct[64][65];
  __shared__ float Hs[64][65];
  int tid = threadIdx.x;
  int bb = blockIdx.x;
  int rt = bb & 255, et = bb >> 8;           // 256 row tiles x 16 e-tiles
  int row0 = rt*64, e0 = et*64;
  int b = row0 >> 12;
  int cidx = (row0 & (T_-1)) >> 6;           // chunk (uniform per block: tile==chunk)
  int cbase = (b*NC_ + cidx)*S_;
  #pragma unroll
  for (int t=0;t<16;t++){
    int fl = t*256+tid; int rr=fl>>6, s=fl&63;
    Ct[rr][s] = ws[WS_C + (e0+rr)*S_ + s];
    Hs[rr][s] = ws[WS_HLOC + (row0+rr)*S_ + s]
              + ws[WS_FAC + rr*S_ + s]*ws[WS_CARRY + cbase + s];
  }
  __syncthreads();
  int ty = tid>>4, tx = tid&15;
  float acc[4][4];
  #pragma unroll
  for (int i=0;i<4;i++)
    #pragma unroll
    for (int j=0;j<4;j++) acc[i][j]=0.f;
  #pragma unroll 4
  for (int s=0;s<64;s++){
    float hv[4], cv[4];
    #pragma unroll
    for (int i=0;i<4;i++) hv[i]=Hs[4*ty+i][s];
    #pragma unroll
    for (int j=0;j<4;j++) cv[j]=Ct[4*tx+j][s];
    #pragma unroll
    for (int i=0;i<4;i++)
      #pragma unroll
      for (int j=0;j<4;j++) acc[i][j] += hv[i]*cv[j];
  }
  float4 d4 = reinterpret_cast<const float4*>(ws + WS_D + e0)[tx];
  #pragma unroll
  for (int i=0;i<4;i++){
    int row = row0 + 4*ty + i;
    float4 x4 = reinterpret_cast<const float4*>(x + row*EMB_ + e0)[tx];
    float4 o;
    o.x = acc[i][0] + d4.x*x4.x;
    o.y = acc[i][1] + d4.y*x4.y;
    o.z = acc[i][2] + d4.z*x4.z;
    o.w = acc[i][3] + d4.w*x4.w;
    reinterpret_cast<float4*>(out + row*EMB_ + e0)[tx] = o;
  }
}

extern "C" void kernel_launch(void* const* d_in, const int* in_sizes, int n_in,
                              void* d_out, int out_size, void* d_ws, size_t ws_size,
                              hipStream_t stream){
  const float* te  = (const float*)d_in[0];
  const float* x   = (const float*)d_in[1];
  const float* W1  = (const float*)d_in[2];
  const float* b1  = (const float*)d_in[3];
  const float* W2  = (const float*)d_in[4];
  const float* b2  = (const float*)d_in[5];
  const float* WA  = (const float*)d_in[6];
  const float* bA  = (const float*)d_in[7];
  const float* WB  = (const float*)d_in[8];
  const float* bB  = (const float*)d_in[9];
  const float* WC  = (const float*)d_in[10];
  const float* bC  = (const float*)d_in[11];
  const float* WD  = (const float*)d_in[12];
  const float* bD  = (const float*)d_in[13];
  const float* Wdl = (const float*)d_in[14];
  const float* bdl = (const float*)d_in[15];
  const float* MA  = (const float*)d_in[16];
  const float* mA  = (const float*)d_in[17];
  const float* MB  = (const float*)d_in[18];
  const float* mB  = (const float*)d_in[19];
  const float* MC  = (const float*)d_in[20];
  const float* mC  = (const float*)d_in[21];
  const float* MD  = (const float*)d_in[22];
  const float* mD  = (const float*)d_in[23];
  const float* Mdl = (const float*)d_in[24];
  const float* mdl = (const float*)d_in[25];
  float* ws  = (float*)d_ws;
  float* out = (float*)d_out;

  k_t1<<<4,128,0,stream>>>(te, W1, b1, ws);
  k_t2<<<4,128,0,stream>>>(W2, b2, ws);
  k_params<<<517,256,0,stream>>>(te, WA,bA, WB,bB, WC,bC, WD,bD, Wdl,bdl,
                                 MA,mA, MB,mB, MC,mC, MD,mD, Mdl,mdl, ws);
  k_scan<<<256,256,0,stream>>>(x, ws);
  k_carry<<<1,256,0,stream>>>(ws);
  k_out<<<4096,256,0,stream>>>(x, ws, out);
}

// Round 2
// 185.302 us; speedup vs baseline: 1.3017x; 1.3017x over previous
//
#include <hip/hip_runtime.h>
#include <math.h>

#define SIN_ 128
#define TEMB_ 512
#define EMB_ 1024
#define S_ 64
#define B_ 4
#define T_ 4096
#define NROW (B_*T_)          // 16384
#define L_ 64                 // scan chunk length
#define NC_ (T_/L_)           // 64 chunks per batch row

// partial flat space: B[0..65535], C[65536..131071], D[131072..132095], A[132096..132159], dl[132160..132223]
#define PSTR 132224
#define FA   132096
#define FDL  132160

// workspace layout (float offsets)
#define WS_T1     0
#define WS_T2     512
#define WS_DELTA  1024
#define WS_ABAR   1088
#define WS_EL     1152
#define WS_FAC    1216                    // 4096
#define WS_D      5312                    // 1024
#define WS_BMT    6336                    // BmT[e][s] = 65536
#define WS_CT     71872                   // CT[s][e]  = 65536
#define WS_P      137408                  // 5*PSTR = 661120
#define WS_HLOC   798528                  // 1048576
#define WS_CHEND  1847104                 // 16384
#define WS_CARRY  1863488                 // 16384
// total 1879872 floats = 7.52 MB

__device__ __forceinline__ float sigmoidf_(float x){ return 1.f/(1.f+expf(-x)); }
__device__ __forceinline__ float softplusf_(float x){ return x>20.f ? x : log1pf(expf(x)); }
__device__ __forceinline__ float4 sig4_(float4 g){
  float4 r; r.x=sigmoidf_(g.x); r.y=sigmoidf_(g.y); r.z=sigmoidf_(g.z); r.w=sigmoidf_(g.w); return r;
}

// ---- t1 = silu(te @ W1 + b1) ----
__global__ void k_t1(const float* __restrict__ te, const float* __restrict__ W1,
                     const float* __restrict__ b1, float* __restrict__ ws){
  __shared__ float ste[SIN_];
  int tid = threadIdx.x;                 // 64 threads, 8 blocks
  ste[tid] = te[tid]; ste[tid+64] = te[tid+64];
  __syncthreads();
  int j = blockIdx.x*64 + tid;
  float a = b1[j];
  #pragma unroll 16
  for (int i=0;i<SIN_;i++) a += ste[i]*W1[i*TEMB_ + j];
  ws[WS_T1 + j] = a * sigmoidf_(a);
}

// ---- t2 = t1 @ W2 + b2 : 8 blocks x 512 thr, 8-way split-K + LDS reduce ----
__global__ __launch_bounds__(512) void k_t2(const float* __restrict__ W2,
                                            const float* __restrict__ b2,
                                            float* __restrict__ ws){
  __shared__ float st1[TEMB_];
  __shared__ float red[8][64];
  int tid = threadIdx.x;
  st1[tid] = ws[WS_T1 + tid];
  __syncthreads();
  int jl = tid & 63, kc = tid >> 6;
  int j = blockIdx.x*64 + jl;
  float p = 0.f;
  #pragma unroll 8
  for (int i=0;i<64;i++){
    int k = kc*64 + i;
    p += st1[k]*W2[k*TEMB_ + j];
  }
  red[kc][jl] = p;
  __syncthreads();
  if (tid < 64){
    float a = b2[blockIdx.x*64 + tid];
    #pragma unroll
    for (int c=0;c<8;c++) a += red[c][tid];
    ws[WS_T2 + blockIdx.x*64 + tid] = a;
  }
}

// ---- split-K partial sums for all big einsums ----
// blocks 0..319   : B  (64 tiles x 5 chunks: 4 a-chunks of K=128 from WB, 1 gate chunk from MB)
// blocks 320..639 : C  (same with WC/MC)
// blocks 640..644 : D  (5 chunks)
// block 645       : A partials (WA, MA)
// block 646       : dl partials (Wdl, Mdl)
__global__ __launch_bounds__(256) void k_partial(
    const float* __restrict__ te,
    const float* __restrict__ WB, const float* __restrict__ MB,
    const float* __restrict__ WC, const float* __restrict__ MC,
    const float* __restrict__ WD, const float* __restrict__ MD,
    const float* __restrict__ WA, const float* __restrict__ MA,
    const float* __restrict__ Wdl, const float* __restrict__ Mdl,
    float* __restrict__ ws){
  __shared__ float st2[TEMB_];
  __shared__ float ste[SIN_];
  int tid = threadIdx.x;
  st2[tid] = ws[WS_T2 + tid];
  st2[tid+256] = ws[WS_T2 + tid + 256];
  if (tid < SIN_) ste[tid] = te[tid];
  __syncthreads();
  int bb = blockIdx.x;
  if (bb < 640){
    int region = bb < 320 ? 0 : 1;
    int lb = bb - region*320;
    int tile = lb/5, ch = lb - tile*5;
    int q = tile*256 + tid;                       // f4 index within 16384
    float4 a = {0.f,0.f,0.f,0.f};
    if (ch < 4){
      const float4* W4 = (const float4*)(region==0 ? WB : WC) + (size_t)(ch*128)*16384 + q;
      const float* coef = st2 + ch*128;
      #pragma unroll 8
      for (int i=0;i<128;i++){
        float4 w = W4[(size_t)i*16384];
        float c = coef[i];
        a.x += c*w.x; a.y += c*w.y; a.z += c*w.z; a.w += c*w.w;
      }
    } else {
      const float4* W4 = (const float4*)(region==0 ? MB : MC) + q;
      #pragma unroll 8
      for (int i=0;i<128;i++){
        float4 w = W4[(size_t)i*16384];
        float c = ste[i];
        a.x += c*w.x; a.y += c*w.y; a.z += c*w.z; a.w += c*w.w;
      }
    }
    ((float4*)(ws + WS_P + ch*PSTR))[region*16384 + q] = a;
  } else if (bb < 645){
    int ch = bb - 640;
    float4 a = {0.f,0.f,0.f,0.f};
    if (ch < 4){
      const float4* W4 = (const float4*)WD + (ch*128)*256 + tid;
      const float* coef = st2 + ch*128;
      #pragma unroll 8
      for (int i=0;i<128;i++){
        float4 w = W4[i*256];
        float c = coef[i];
        a.x += c*w.x; a.y += c*w.y; a.z += c*w.z; a.w += c*w.w;
      }
    } else {
      const float4* W4 = (const float4*)MD + tid;
      #pragma unroll 8
      for (int i=0;i<128;i++){
        float4 w = W4[i*256];
        float c = ste[i];
        a.x += c*w.x; a.y += c*w.y; a.z += c*w.z; a.w += c*w.w;
      }
    }
    ((float4*)(ws + WS_P + ch*PSTR))[32768 + tid] = a;
  } else if (bb == 645){
    int c = tid>>6, s = tid&63;
    float p = 0.f;
    #pragma unroll 8
    for (int i=0;i<128;i++) p += st2[c*128+i]*WA[(c*128+i)*64 + s];
    ws[WS_P + c*PSTR + FA + s] = p;
    if (tid < 64){
      float g = 0.f;
      #pragma unroll 8
      for (int i=0;i<128;i++) g += ste[i]*MA[i*64 + s];
      ws[WS_P + 4*PSTR + FA + s] = g;
    }
  } else {
    int c = tid>>6, s = tid&63;
    float p = 0.f;
    #pragma unroll 8
    for (int i=0;i<128;i++) p += st2[c*128+i]*Wdl[(c*128+i)*64 + s];
    ws[WS_P + c*PSTR + FDL + s] = p;
    if (tid < 64){
      float g = 0.f;
      #pragma unroll 8
      for (int i=0;i<128;i++) g += ste[i]*Mdl[i*64 + s];
      ws[WS_P + 4*PSTR + FDL + s] = g;
    }
  }
}

// ---- finalize: bias + gate, write BmT[e][s], CT[s][e], D; A/delta/abar/eL/fac ----
__global__ __launch_bounds__(256) void k_finalize(
    const float* __restrict__ bB, const float* __restrict__ mB,
    const float* __restrict__ bC, const float* __restrict__ mC,
    const float* __restrict__ bD, const float* __restrict__ mD,
    const float* __restrict__ bA_, const float* __restrict__ mA_,
    const float* __restrict__ bdl, const float* __restrict__ mdl,
    float* __restrict__ ws){
  int tid = threadIdx.x, bb = blockIdx.x;
  if (bb < 128){
    int q = bb*256 + tid;                          // f4 idx in [0,32768)
    float4 a = ((const float4*)(ws + WS_P + 0*PSTR))[q];
    float4 a1 = ((const float4*)(ws + WS_P + 1*PSTR))[q];
    float4 a2 = ((const float4*)(ws + WS_P + 2*PSTR))[q];
    float4 a3 = ((const float4*)(ws + WS_P + 3*PSTR))[q];
    float4 g  = ((const float4*)(ws + WS_P + 4*PSTR))[q];
    a.x += a1.x+a2.x+a3.x; a.y += a1.y+a2.y+a3.y;
    a.z += a1.z+a2.z+a3.z; a.w += a1.w+a2.w+a3.w;
    if (q < 16384){
      float4 b4 = ((const float4*)bB)[q];
      float4 m4 = ((const float4*)mB)[q];
      float4 sg = sig4_(make_float4(g.x+m4.x, g.y+m4.y, g.z+m4.z, g.w+m4.w));
      float4 v = make_float4((a.x+b4.x)*sg.x,(a.y+b4.y)*sg.y,(a.z+b4.z)*sg.z,(a.w+b4.w)*sg.w);
      int o = q*4; int s = o>>10; int e = o&1023;
      ws[WS_BMT + (e+0)*64 + s] = v.x;
      ws[WS_BMT + (e+1)*64 + s] = v.y;
      ws[WS_BMT + (e+2)*64 + s] = v.z;
      ws[WS_BMT + (e+3)*64 + s] = v.w;
    } else {
      int q2 = q - 16384;
      float4 b4 = ((const float4*)bC)[q2];
      float4 m4 = ((const float4*)mC)[q2];
      float4 sg = sig4_(make_float4(g.x+m4.x, g.y+m4.y, g.z+m4.z, g.w+m4.w));
      float4 v = make_float4((a.x+b4.x)*sg.x,(a.y+b4.y)*sg.y,(a.z+b4.z)*sg.z,(a.w+b4.w)*sg.w);
      int o = q2*4; int e = o>>6; int s = o&63;
      ws[WS_CT + (s+0)*1024 + e] = v.x;
      ws[WS_CT + (s+1)*1024 + e] = v.y;
      ws[WS_CT + (s+2)*1024 + e] = v.z;
      ws[WS_CT + (s+3)*1024 + e] = v.w;
    }
  } else if (bb == 128){
    int q = 32768 + tid;
    float4 a = ((const float4*)(ws + WS_P + 0*PSTR))[q];
    float4 a1 = ((const float4*)(ws + WS_P + 1*PSTR))[q];
    float4 a2 = ((const float4*)(ws + WS_P + 2*PSTR))[q];
    float4 a3 = ((const float4*)(ws + WS_P + 3*PSTR))[q];
    float4 g  = ((const float4*)(ws + WS_P + 4*PSTR))[q];
    a.x += a1.x+a2.x+a3.x; a.y += a1.y+a2.y+a3.y;
    a.z += a1.z+a2.z+a3.z; a.w += a1.w+a2.w+a3.w;
    float4 b4 = ((const float4*)bD)[tid];
    float4 m4 = ((const float4*)mD)[tid];
    float4 sg = sig4_(make_float4(g.x+m4.x, g.y+m4.y, g.z+m4.z, g.w+m4.w));
    float4 v = make_float4((a.x+b4.x)*sg.x,(a.y+b4.y)*sg.y,(a.z+b4.z)*sg.z,(a.w+b4.w)*sg.w);
    ((float4*)(ws + WS_D))[tid] = v;
  } else {
    __shared__ float sda[64];
    if (tid < 64){
      int s = tid;
      float sa = ws[WS_P+0*PSTR+FA+s]+ws[WS_P+1*PSTR+FA+s]+ws[WS_P+2*PSTR+FA+s]+ws[WS_P+3*PSTR+FA+s];
      float ga = ws[WS_P+4*PSTR+FA+s];
      float A = -softplusf_(sa + bA_[s]) * sigmoidf_(ga + mA_[s]);
      float sd = ws[WS_P+0*PSTR+FDL+s]+ws[WS_P+1*PSTR+FDL+s]+ws[WS_P+2*PSTR+FDL+s]+ws[WS_P+3*PSTR+FDL+s];
      float gd = ws[WS_P+4*PSTR+FDL+s];
      float delta = (softplusf_(sd + bdl[s]) + 1e-4f) * sigmoidf_(gd + mdl[s]);
      float da = delta * A;
      sda[s] = da;
      ws[WS_DELTA+s] = delta;
      ws[WS_ABAR+s]  = expf(da);
      ws[WS_EL+s]    = expf(64.f*da);
    }
    __syncthreads();
    for (int idx=tid; idx<L_*S_; idx+=256){
      int tl = idx>>6, s = idx&63;
      ws[WS_FAC+idx] = expf((float)(tl+1)*sda[s]);
    }
  }
}

// ---- per-(b,chunk): u = delta ⊙ (x @ Bm^T), zero-state local scan ----
__global__ __launch_bounds__(256) void k_scan(const float* __restrict__ x, float* __restrict__ ws){
  __shared__ float Xs[64][68];     // [trow][k]
  __shared__ float BsT[64][68];    // [k][s]
  __shared__ float Us[64][65];     // [trow][s]
  __shared__ float sdl[S_], sab[S_];
  int tid = threadIdx.x;
  int bb = blockIdx.x;                       // b*64 + c
  int row0 = (bb>>6)*T_ + (bb&63)*64;
  if (tid<64){ sdl[tid]=ws[WS_DELTA+tid]; sab[tid]=ws[WS_ABAR+tid]; }
  float acc[4][4];
  #pragma unroll
  for (int i=0;i<4;i++)
    #pragma unroll
    for (int j=0;j<4;j++) acc[i][j]=0.f;
  int ty = tid>>4, tx = tid&15;
  const float4* x4 = (const float4*)x;
  const float4* BmT4 = (const float4*)(ws + WS_BMT);
  for (int kk=0; kk<EMB_; kk+=64){
    #pragma unroll
    for (int t=0;t<4;t++){
      int fl = t*256+tid; int rr = fl>>4, cq = fl&15;
      float4 xv = x4[(size_t)(row0+rr)*256 + (kk>>2) + cq];
      *(float4*)&Xs[rr][cq*4] = xv;
      float4 bv = BmT4[(size_t)(kk+rr)*16 + cq];
      *(float4*)&BsT[rr][cq*4] = bv;
    }
    __syncthreads();
    #pragma unroll 8
    for (int k=0;k<64;k++){
      float4 b4 = *(const float4*)&BsT[k][4*tx];
      float x0 = Xs[4*ty+0][k], x1 = Xs[4*ty+1][k], x2 = Xs[4*ty+2][k], x3 = Xs[4*ty+3][k];
      acc[0][0]+=x0*b4.x; acc[0][1]+=x0*b4.y; acc[0][2]+=x0*b4.z; acc[0][3]+=x0*b4.w;
      acc[1][0]+=x1*b4.x; acc[1][1]+=x1*b4.y; acc[1][2]+=x1*b4.z; acc[1][3]+=x1*b4.w;
      acc[2][0]+=x2*b4.x; acc[2][1]+=x2*b4.y; acc[2][2]+=x2*b4.z; acc[2][3]+=x2*b4.w;
      acc[3][0]+=x3*b4.x; acc[3][1]+=x3*b4.y; acc[3][2]+=x3*b4.z; acc[3][3]+=x3*b4.w;
    }
    __syncthreads();
  }
  #pragma unroll
  for (int i=0;i<4;i++)
    #pragma unroll
    for (int j=0;j<4;j++)
      Us[4*ty+i][4*tx+j] = acc[i][j]*sdl[4*tx+j];
  __syncthreads();
  if (tid<64){
    int s = tid; float h = 0.f, ab = sab[s];
    for (int t=0;t<64;t++){
      h = fmaf(ab, h, Us[t][s]);
      ws[WS_HLOC + (row0+t)*S_ + s] = h;
    }
    ws[WS_CHEND + bb*S_ + s] = h;
  }
}

// ---- chain chunk boundary states ----
__global__ void k_carry(float* __restrict__ ws){
  __shared__ float ch[B_*NC_*S_];            // 64 KB
  int tid = threadIdx.x;                     // 256 = (b,s)
  for (int i=tid;i<B_*NC_*S_;i+=256) ch[i] = ws[WS_CHEND + i];
  __syncthreads();
  int b = tid>>6, s = tid&63;
  float el = ws[WS_EL + s];
  float carry = 0.f;
  #pragma unroll 8
  for (int c=0;c<NC_;c++){
    int idx = (b*NC_ + c)*S_ + s;
    ws[WS_CARRY + idx] = carry;
    carry = el*carry + ch[idx];
  }
}

// ---- out = (hloc + fac*carry) @ C^T + D*x ----
__global__ __launch_bounds__(256) void k_out(const float* __restrict__ x,
                                             const float* __restrict__ ws,
                                             float* __restrict__ out){
  __shared__ float Cts[64][68];    // [s][elocal]
  __shared__ float Hs[64][68];     // [trow][s]
  int tid = threadIdx.x;
  int bb = blockIdx.x;
  int rt = bb & 255, et = bb >> 8;           // 256 row tiles x 16 e-tiles
  int row0 = rt*64, e0 = et*64;
  int b = row0 >> 12;
  int cidx = (row0 & (T_-1)) >> 6;
  int cbase4 = ((b*NC_ + cidx)*S_) >> 2;
  const float4* hl4 = (const float4*)(ws + WS_HLOC);
  const float4* fc4 = (const float4*)(ws + WS_FAC);
  const float4* cr4 = (const float4*)(ws + WS_CARRY);
  const float4* CT4 = (const float4*)(ws + WS_CT);
  #pragma unroll
  for (int t=0;t<4;t++){
    int fl = t*256+tid; int rr = fl>>4, q = fl&15;
    float4 h = hl4[(size_t)(row0+rr)*16 + q];
    float4 f = fc4[rr*16 + q];
    float4 c = cr4[cbase4 + q];
    float4 hv = make_float4(h.x+f.x*c.x, h.y+f.y*c.y, h.z+f.z*c.z, h.w+f.w*c.w);
    *(float4*)&Hs[rr][q*4] = hv;
    float4 ct = CT4[(size_t)rr*256 + (e0>>2) + q];
    *(float4*)&Cts[rr][q*4] = ct;
  }
  __syncthreads();
  int ty = tid>>4, tx = tid&15;
  float acc[4][4];
  #pragma unroll
  for (int i=0;i<4;i++)
    #pragma unroll
    for (int j=0;j<4;j++) acc[i][j]=0.f;
  #pragma unroll 8
  for (int s=0;s<64;s++){
    float4 c4 = *(const float4*)&Cts[s][4*tx];
    float h0 = Hs[4*ty+0][s], h1 = Hs[4*ty+1][s], h2 = Hs[4*ty+2][s], h3 = Hs[4*ty+3][s];
    acc[0][0]+=h0*c4.x; acc[0][1]+=h0*c4.y; acc[0][2]+=h0*c4.z; acc[0][3]+=h0*c4.w;
    acc[1][0]+=h1*c4.x; acc[1][1]+=h1*c4.y; acc[1][2]+=h1*c4.z; acc[1][3]+=h1*c4.w;
    acc[2][0]+=h2*c4.x; acc[2][1]+=h2*c4.y; acc[2][2]+=h2*c4.z; acc[2][3]+=h2*c4.w;
    acc[3][0]+=h3*c4.x; acc[3][1]+=h3*c4.y; acc[3][2]+=h3*c4.z; acc[3][3]+=h3*c4.w;
  }
  float4 d4 = ((const float4*)(ws + WS_D))[(e0>>2) + tx];
  #pragma unroll
  for (int i=0;i<4;i++){
    int row = row0 + 4*ty + i;
    float4 x4v = reinterpret_cast<const float4*>(x + (size_t)row*EMB_ + e0)[tx];
    float4 o;
    o.x = acc[i][0] + d4.x*x4v.x;
    o.y = acc[i][1] + d4.y*x4v.y;
    o.z = acc[i][2] + d4.z*x4v.z;
    o.w = acc[i][3] + d4.w*x4v.w;
    reinterpret_cast<float4*>(out + (size_t)row*EMB_ + e0)[tx] = o;
  }
}

extern "C" void kernel_launch(void* const* d_in, const int* in_sizes, int n_in,
                              void* d_out, int out_size, void* d_ws, size_t ws_size,
                              hipStream_t stream){
  const float* te  = (const float*)d_in[0];
  const float* x   = (const float*)d_in[1];
  const float* W1  = (const float*)d_in[2];
  const float* b1  = (const float*)d_in[3];
  const float* W2  = (const float*)d_in[4];
  const float* b2  = (const float*)d_in[5];
  const float* WA  = (const float*)d_in[6];
  const float* bA  = (const float*)d_in[7];
  const float* WB  = (const float*)d_in[8];
  const float* bB  = (const float*)d_in[9];
  const float* WC  = (const float*)d_in[10];
  const float* bC  = (const float*)d_in[11];
  const float* WD  = (const float*)d_in[12];
  const float* bD  = (const float*)d_in[13];
  const float* Wdl = (const float*)d_in[14];
  const float* bdl = (const float*)d_in[15];
  const float* MA  = (const float*)d_in[16];
  const float* mA  = (const float*)d_in[17];
  const float* MB  = (const float*)d_in[18];
  const float* mB  = (const float*)d_in[19];
  const float* MC  = (const float*)d_in[20];
  const float* mC  = (const float*)d_in[21];
  const float* MD  = (const float*)d_in[22];
  const float* mD  = (const float*)d_in[23];
  const float* Mdl = (const float*)d_in[24];
  const float* mdl = (const float*)d_in[25];
  float* ws  = (float*)d_ws;
  float* out = (float*)d_out;

  k_t1<<<8,64,0,stream>>>(te, W1, b1, ws);
  k_t2<<<8,512,0,stream>>>(W2, b2, ws);
  k_partial<<<647,256,0,stream>>>(te, WB,MB, WC,MC, WD,MD, WA,MA, Wdl,Mdl, ws);
  k_finalize<<<130,256,0,stream>>>(bB,mB, bC,mC, bD,mD, bA,mA, bdl,mdl, ws);
  k_scan<<<256,256,0,stream>>>(x, ws);
  k_carry<<<1,256,0,stream>>>(ws);
  k_out<<<4096,256,0,stream>>>(x, ws, out);
}